// Round 15
// baseline (169.658 us; speedup 1.0000x reference)
//
#include <hip/hip_runtime.h>
#include <math.h>

// Round 21: halve per-thread state by GEOMETRY (R18's 68-VGPR structure cannot
// be tricked under the 64 cliff — R19 forced cap spilled, R20 "reductions"
// raised it to 80). One residue per thread:
//  - 512-thread blocks (8 waves), thread t owns residue t-1 (t=0: init block).
//  - per-thread: 9 params + P(12) + temp(12) ~= 45-52 live -> natural <=64.
//  - own-index coalesced loads + shfl_up(1) shift into residue t-1's frame
//    (phi[r+1] = phi[t]: own value, no shift). lane0 fallback loads per wave.
//  - phase A: 3 serial steps (no intra-thread ILP; TLP covers it at 32
//    resident waves/CU).
//  - 6-level scan, 7 wave totals cumulated by thread 0 (R20-proven), replay
//    by recompute, LDS-staged scalar sweep (2KB/block-round, coalesced).
// Tripwires: VGPR_Count <= 64, WRITE_SIZE == 73728 KB exactly.

#define LCH 512

struct Xf { float r[9]; float t[3]; };

__device__ __forceinline__ Xf xf_compose(const Xf& A, const Xf& B) {
  Xf C;
#pragma unroll
  for (int i = 0; i < 3; ++i) {
    float a0 = A.r[3*i+0], a1 = A.r[3*i+1], a2 = A.r[3*i+2];
    C.r[3*i+0] = a0*B.r[0] + a1*B.r[3] + a2*B.r[6];
    C.r[3*i+1] = a0*B.r[1] + a1*B.r[4] + a2*B.r[7];
    C.r[3*i+2] = a0*B.r[2] + a1*B.r[5] + a2*B.r[8];
    C.t[i]     = a0*B.t[0] + a1*B.t[1] + a2*B.t[2] + A.t[i];
  }
  return C;
}

// P := P o Delta(theta, len, tau), sparsity-aware (~31 FMA).
__device__ __forceinline__ void xf_step(Xf& P, float theta, float len, float tau) {
  float st, ct, sx, cx;
  __sincosf(theta, &st, &ct);
  __sincosf(tau, &sx, &cx);
  float ux = -ct, uy = cx*st, uz = sx*st;      // delta col0 (= d_local / L)
  float v0 = -st, v1 = -ct*cx, v2 = -ct*sx;    // delta col1; col2 = (0,-sx,cx)
  float c00 = P.r[0]*ux + P.r[1]*uy + P.r[2]*uz;
  float c10 = P.r[3]*ux + P.r[4]*uy + P.r[5]*uz;
  float c20 = P.r[6]*ux + P.r[7]*uy + P.r[8]*uz;
  float c01 = P.r[0]*v0 + P.r[1]*v1 + P.r[2]*v2;
  float c11 = P.r[3]*v0 + P.r[4]*v1 + P.r[5]*v2;
  float c21 = P.r[6]*v0 + P.r[7]*v1 + P.r[8]*v2;
  float c02 = P.r[2]*cx - P.r[1]*sx;
  float c12 = P.r[5]*cx - P.r[4]*sx;
  float c22 = P.r[8]*cx - P.r[7]*sx;
  P.t[0] += len*c00; P.t[1] += len*c10; P.t[2] += len*c20;
  P.r[0]=c00; P.r[1]=c01; P.r[2]=c02;
  P.r[3]=c10; P.r[4]=c11; P.r[5]=c12;
  P.r[6]=c20; P.r[7]=c21; P.r[8]=c22;
}

__device__ __forceinline__ void xf_set_delta(Xf& P, float theta, float len, float tau) {
  float st, ct, sx, cx;
  __sincosf(theta, &st, &ct);
  __sincosf(tau, &sx, &cx);
  float ux = -ct, uy = cx*st, uz = sx*st;
  P.r[0]=ux; P.r[1]=-st;    P.r[2]=0.f;
  P.r[3]=uy; P.r[4]=-ct*cx; P.r[5]=-sx;
  P.r[6]=uz; P.r[7]=-ct*sx; P.r[8]=cx;
  P.t[0]=len*ux; P.t[1]=len*uy; P.t[2]=len*uz;
}

__device__ __forceinline__ void xf_identity(Xf& A) {
  A.r[0]=1.f; A.r[1]=0.f; A.r[2]=0.f;
  A.r[3]=0.f; A.r[4]=1.f; A.r[5]=0.f;
  A.r[6]=0.f; A.r[7]=0.f; A.r[8]=1.f;
  A.t[0]=0.f; A.t[1]=0.f; A.t[2]=0.f;
}

__device__ __forceinline__ Xf xf_shfl_up(const Xf& P, int d) {
  Xf O;
#pragma unroll
  for (int i = 0; i < 9; ++i) O.r[i] = __shfl_up(P.r[i], d, 64);
#pragma unroll
  for (int i = 0; i < 3; ++i) O.t[i] = __shfl_up(P.t[i], d, 64);
  return O;
}

__global__ __launch_bounds__(512) void nerf_r21_kernel(
    const float* __restrict__ g_phi, const float* __restrict__ g_psi,
    const float* __restrict__ g_omg, const float* __restrict__ g_bl,
    const float* __restrict__ g_ba, float* __restrict__ g_out)
{
  __shared__ float s_tot[84];           // 7 wave totals -> cumulative prefixes
  __shared__ float s_out[4608];         // linear output staging (18 KB)

  const int t    = threadIdx.x;         // 0..511
  const int lane = t & 63;
  const int wave = t >> 6;
  const int chain = blockIdx.x;

  const float* phir = g_phi + (size_t)chain * LCH;
  const float* psir = g_psi + (size_t)chain * LCH;
  const float* omgr = g_omg + (size_t)chain * LCH;
  const float* blr  = g_bl  + (size_t)chain * (LCH*3);
  const float* bar  = g_ba  + (size_t)chain * (LCH*3);

  // ---- own-index coalesced loads ----
  float ps  = psir[t];
  float om  = omgr[t];
  float ph  = phir[t];                  // = phi[r+1] for r = t-1 (no shift)
  float bl0 = blr[3*t], bl1 = blr[3*t+1], bl2 = blr[3*t+2];
  float ba0 = bar[3*t], ba1 = bar[3*t+1], ba2 = bar[3*t+2];

  // ---- shift into residue r = t-1 frame via neighbor registers ----
  float psA  = __shfl_up(ps, 1, 64);
  float omA  = __shfl_up(om, 1, 64);
  float blA0 = __shfl_up(bl0, 1, 64);
  float blA1 = __shfl_up(bl1, 1, 64);
  float blA2 = __shfl_up(bl2, 1, 64);
  float baA0 = __shfl_up(ba0, 1, 64);
  float baA1 = __shfl_up(ba1, 1, 64);
  float baA2 = __shfl_up(ba2, 1, 64);
  if (lane == 0 && t != 0) {            // cross-wave edge (t = 64k)
    psA  = psir[t - 1];
    omA  = omgr[t - 1];
    blA0 = blr[3*t - 3]; blA1 = blr[3*t - 2]; blA2 = blr[3*t - 1];
    baA0 = bar[3*t - 3]; baA1 = bar[3*t - 2]; baA2 = bar[3*t - 1];
  }
  // (t==0: params junk; chain reset to identity below)

  // ---- Phase A: residue (t-1)'s three deltas ----
  // N(theta=ba1,L=bl2,tau=psi) CA(ba2,bl0,omg) C(ba0,bl1,phi[r+1])
  Xf P;
  xf_set_delta(P, baA1, blA2, psA);
  xf_step(P, baA2, blA0, omA);
  xf_step(P, baA0, blA1, ph);
  if (t == 0) xf_identity(P);           // discard pre-roll chain

  // ---- intra-wave inclusive scan (non-commutative), fully unrolled ----
#pragma unroll
  for (int d = 1; d < 64; d <<= 1) {
    Xf O = xf_shfl_up(P, d);
    if (lane >= d) P = xf_compose(O, P);
  }

  // wave totals (waves 0..6) -> LDS
  if (lane == 63 && wave < 7) {
#pragma unroll
    for (int i = 0; i < 9; ++i) s_tot[12*wave + i] = P.r[i];
#pragma unroll
    for (int i = 0; i < 3; ++i) s_tot[12*wave + 9 + i] = P.t[i];
  }
  Xf E = xf_shfl_up(P, 1);   // within-wave exclusive (junk for lane 0)
  __syncthreads();

  // ---- thread 0: cumulate wave prefixes in LDS (slot w -> T0 o..o Tw) ----
  if (t == 0) {
    Xf C;
#pragma unroll
    for (int i = 0; i < 9; ++i) C.r[i] = s_tot[i];
#pragma unroll
    for (int i = 0; i < 3; ++i) C.t[i] = s_tot[9+i];
    for (int w = 1; w < 7; ++w) {
      Xf T;
#pragma unroll
      for (int i = 0; i < 9; ++i) T.r[i] = s_tot[12*w + i];
#pragma unroll
      for (int i = 0; i < 3; ++i) T.t[i] = s_tot[12*w + 9 + i];
      C = xf_compose(C, T);
#pragma unroll
      for (int i = 0; i < 9; ++i) s_tot[12*w + i] = C.r[i];
#pragma unroll
      for (int i = 0; i < 3; ++i) s_tot[12*w + 9 + i] = C.t[i];
    }
  }
  __syncthreads();

  // ---- prefix A = I0 [o C_wave] [o E] ----
  Xf A;
  A.r[0]=-0.849699f; A.r[1]=-0.223843f; A.r[2]=-0.477398f;
  A.r[3]=-0.019221f; A.r[4]= 0.917962f; A.r[5]=-0.396206f;
  A.r[6]= 0.526919f; A.r[7]=-0.327477f; A.r[8]=-0.784291f;
  A.t[0]=15.685f; A.t[1]=12.755f; A.t[2]=5.133f;
  if (wave >= 1) {
    const int o = 12 * (wave - 1);
    Xf T;
#pragma unroll
    for (int i = 0; i < 9; ++i) T.r[i] = s_tot[o + i];
#pragma unroll
    for (int i = 0; i < 3; ++i) T.t[i] = s_tot[o + 9 + i];
    A = xf_compose(A, T);
  }
  if (lane > 0) A = xf_compose(A, E);

  // ---- replay by recompute: 3 serial steps, stage 9 floats into LDS ----
  float* o = s_out + 9 * t;
  if (t == 0) {
    o[0]=17.047f; o[1]=14.099f; o[2]=3.625f;
    o[3]=16.967f; o[4]=12.784f; o[5]=4.338f;
    o[6]=15.685f; o[7]=12.755f; o[8]=5.133f;
  } else {
    xf_step(A, baA1, blA2, psA);
    o[0]=A.t[0]; o[1]=A.t[1]; o[2]=A.t[2];
    xf_step(A, baA2, blA0, omA);
    o[3]=A.t[0]; o[4]=A.t[1]; o[5]=A.t[2];
    xf_step(A, baA0, blA1, ph);
    o[6]=A.t[0]; o[7]=A.t[1]; o[8]=A.t[2];
  }
  __syncthreads();

  // ---- coalesced scalar sweep (2KB contiguous per block round) ----
  float* orow = g_out + (size_t)chain * 4608;
#pragma unroll
  for (int q = 0; q < 9; ++q) {
    const int g = t + 512*q;
    orow[g] = s_out[g];
  }
}

extern "C" void kernel_launch(void* const* d_in, const int* in_sizes, int n_in,
                              void* d_out, int out_size, void* d_ws, size_t ws_size,
                              hipStream_t stream) {
  const float* phi = (const float*)d_in[0];
  const float* psi = (const float*)d_in[1];
  const float* omg = (const float*)d_in[2];
  const float* bl  = (const float*)d_in[3];
  const float* ba  = (const float*)d_in[4];
  float* out = (float*)d_out;
  const int B = in_sizes[0] / LCH;          // 4096 chains
  hipLaunchKernelGGL(nerf_r21_kernel, dim3(B), dim3(512), 0, stream,
                     phi, psi, omg, bl, ba, out);
}